// Round 7
// baseline (1010.855 us; speedup 1.0000x reference)
//
#include <hip/hip_runtime.h>

#define TT 2048
#define BB 64
#define HH 256   // EMB == HID == 256

typedef _Float16 half2_t __attribute__((ext_vector_type(2)));
typedef _Float16 half8_t __attribute__((ext_vector_type(8)));
typedef float f32x4 __attribute__((ext_vector_type(4)));

// ---------------------------------------------------------------------------
// prep: transpose + fp16-convert W_ih and W_hh into [N][K] row-major.
// ---------------------------------------------------------------------------
__global__ void prep_kernel(const float* __restrict__ Wih, const float* __restrict__ Whh,
                            _Float16* __restrict__ WihT, _Float16* __restrict__ WhhT) {
  const int n = blockIdx.x;   // output column
  const int k = threadIdx.x;  // input row
  WihT[n * HH + k] = (_Float16)Wih[k * HH + n];
  WhhT[n * HH + k] = (_Float16)Whh[k * HH + n];
}

// ---------------------------------------------------------------------------
// Part A: U[t][b][n] = (emb[source[b][t]] @ W_ih)[n] + b_ih[n] + b_hh[n], fp16.
// (unchanged — verified correct; scan dominates runtime)
// ---------------------------------------------------------------------------
__global__ __launch_bounds__(256, 2) void embed_gemm_kernel(
    const int* __restrict__ source, const float* __restrict__ emb,
    const _Float16* __restrict__ WihT, const float* __restrict__ b_ih,
    const float* __restrict__ b_hh, _Float16* __restrict__ U) {
  const int t = blockIdx.x;
  const int nbase = blockIdx.y * 64;
  __shared__ __align__(16) _Float16 Bs[64][280];

  const int tid = threadIdx.x;
  for (int c = tid; c < 64 * 32; c += 256) {
    const int n = c >> 5;
    const int ko = (c & 31) * 8;
    *(half8_t*)&Bs[n][ko] = *(const half8_t*)(WihT + (size_t)(nbase + n) * HH + ko);
  }
  __syncthreads();

  const int lane = tid & 63;
  const int wave = tid >> 6;
  const int row16 = lane & 15;
  const int quad = lane >> 4;
  const int b = wave * 16 + row16;              // A-fragment row = batch
  const int src = source[b * TT + t];           // source is [B][T]
  const float* arow = emb + (size_t)src * HH + quad * 8;

  f32x4 acc[4];
#pragma unroll
  for (int ct = 0; ct < 4; ++ct) acc[ct] = (f32x4){0.f, 0.f, 0.f, 0.f};

#pragma unroll
  for (int kt = 0; kt < 8; ++kt) {
    const float4 x0 = *(const float4*)(arow + kt * 32);
    const float4 x1 = *(const float4*)(arow + kt * 32 + 4);
    half8_t af;
    af[0] = (_Float16)x0.x; af[1] = (_Float16)x0.y;
    af[2] = (_Float16)x0.z; af[3] = (_Float16)x0.w;
    af[4] = (_Float16)x1.x; af[5] = (_Float16)x1.y;
    af[6] = (_Float16)x1.z; af[7] = (_Float16)x1.w;
#pragma unroll
    for (int ct = 0; ct < 4; ++ct) {
      const half8_t bf = *(const half8_t*)&Bs[ct * 16 + row16][quad * 8 + kt * 32];
      acc[ct] = __builtin_amdgcn_mfma_f32_16x16x32_f16(af, bf, acc[ct], 0, 0, 0);
    }
  }

#pragma unroll
  for (int ct = 0; ct < 4; ++ct) {
    const int nn = nbase + ct * 16 + row16;     // C col = lane&15
    const float bias = b_ih[nn] + b_hh[nn];
#pragma unroll
    for (int r = 0; r < 4; ++r) {
      const int bb = wave * 16 + quad * 4 + r;  // C row = quad*4 + reg
      U[((size_t)t * BB + bb) * HH + nn] = (_Float16)(acc[ct][r] + bias);
    }
  }
}

// ---------------------------------------------------------------------------
// Part B: recurrence — R16: R15 + split accumulator chains + kZero C-init.
//   R15 post-mortem: pre-issue worked (step 942->896). Remaining gap vs the
//   620-cy MFMA floor: MfmaUtil 57%-of-active vs expected 69% -> ~110 cy of
//   stalls INSIDE the MFMA phase. Candidate: dependent-MFMA spacing — 4
//   interleaved chains put dependent MFMAs 4x19.4=78 cy apart; if 16x16x32
//   D->C latency > 78 cy, every MFMA stalls. Fixes:
//     1. ca[tt]/cb[tt] split chains (even/odd chunks): 8 independent chains,
//        dep spacing 155 cy. +16 AGPR, +4 adds at finalize.
//     2. kZero as C-in on each chain's first MFMA: kills the 16-op
//        accumulator zero-init in the write->read gap.
//     3. hoA consumed before hoB's pin; cross-chunk batch pin dropped so the
//        compiler emits incremental lgkmcnt (it does this well per guide).
//   Everything else identical to R15 (AGPR weights, chunk rotation, one raw
//   barrier/step, top-of-chunk u-prefetch).
//   Predicted step ~740-780 cy (was 896). If unchanged: dep-stall theory
//   falsified -> residual is barrier/LDS-latency only.
// ---------------------------------------------------------------------------
__global__ __launch_bounds__(256)
__attribute__((amdgpu_waves_per_eu(1, 1)))
void rnn_scan_kernel(
    const _Float16* __restrict__ U, const _Float16* __restrict__ WhhT,
    float* __restrict__ out) {
  const int b = blockIdx.x;
  const int tid = threadIdx.x;
  const int w = tid >> 6;
  const int l = tid & 63;
  const int col = l & 15;    // n within tile
  const int quad = l >> 4;   // MFMA quad

  __shared__ __align__(16) _Float16 hbuf[2][HH];  // 1 KB ping-pong

  // wb[tt][j]: B-frag for n-tile 64w+16tt, k-chunk c=(2w+j)&7 (own chunks at
  // j=0,1). Lane reads WhhT[(64w+16tt+col)][32c + quad*8 .. +8] (16B aligned).
  half8_t wb[4][8];
#pragma unroll
  for (int tt = 0; tt < 4; ++tt) {
    const _Float16* base = WhhT + (size_t)(64 * w + 16 * tt + col) * HH + quad * 8;
#pragma unroll
    for (int j = 0; j < 8; ++j) {
      const int c = (2 * w + j) & 7;
      wb[tt][j] = *(const half8_t*)(base + 32 * c);
    }
  }
  // Pin into AGPRs ("a"): one-time v_accvgpr_write; MFMA reads B from AGPR.
  asm volatile("" : "+a"(wb[0][0]), "+a"(wb[0][1]), "+a"(wb[0][2]), "+a"(wb[0][3]),
                    "+a"(wb[0][4]), "+a"(wb[0][5]), "+a"(wb[0][6]), "+a"(wb[0][7]),
                    "+a"(wb[1][0]), "+a"(wb[1][1]), "+a"(wb[1][2]), "+a"(wb[1][3]),
                    "+a"(wb[1][4]), "+a"(wb[1][5]), "+a"(wb[1][6]), "+a"(wb[1][7]));
  asm volatile("" : "+a"(wb[2][0]), "+a"(wb[2][1]), "+a"(wb[2][2]), "+a"(wb[2][3]),
                    "+a"(wb[2][4]), "+a"(wb[2][5]), "+a"(wb[2][6]), "+a"(wb[2][7]),
                    "+a"(wb[3][0]), "+a"(wb[3][1]), "+a"(wb[3][2]), "+a"(wb[3][3]),
                    "+a"(wb[3][4]), "+a"(wb[3][5]), "+a"(wb[3][6]), "+a"(wb[3][7]));

  // h-read offsets (halfs): chunk (2w+j)&7 at 32*c + 8*quad.
  const int oO0 = 32 * ((2 * w + 0) & 7) + 8 * quad;  // own chunk j=0
  const int oO1 = 32 * ((2 * w + 1) & 7) + 8 * quad;  // own chunk j=1
  const int oX2 = 32 * ((2 * w + 2) & 7) + 8 * quad;
  const int oX3 = 32 * ((2 * w + 3) & 7) + 8 * quad;
  const int oX4 = 32 * ((2 * w + 4) & 7) + 8 * quad;
  const int oX5 = 32 * ((2 * w + 5) & 7) + 8 * quad;
  const int oX6 = 32 * ((2 * w + 6) & 7) + 8 * quad;
  const int oX7 = 32 * ((2 * w + 7) & 7) + 8 * quad;

  hbuf[0][tid] = (_Float16)0.f;  // h0 = 0

  // Thread tid finalizes output n = tid: u stream is per-thread contiguous.
  const _Float16* Up = U + b * HH + tid;  // step stride = BB*HH halfs
  _Float16 uc[8], un[8];
#pragma unroll
  for (int s = 0; s < 8; ++s) uc[s] = Up[(size_t)s * (BB * HH)];

  float hn = 0.f;
  const f32x4 kZero = (f32x4){0.f, 0.f, 0.f, 0.f};  // hoisted C-init
  f32x4 ca[4], cb[4];  // split chains: even chunks -> ca, odd -> cb

  __syncthreads();

  // ---- prologue: own-chunk frags of h_0 + 8 pre-issued MFMAs (step 0) ----
  {
    half8_t hoA = *(const half8_t*)(hbuf[0] + oO0);
    half8_t hoB = *(const half8_t*)(hbuf[0] + oO1);
    asm volatile("" : "+v"(hoA));
#pragma unroll
    for (int tt = 0; tt < 4; ++tt)
      ca[tt] = __builtin_amdgcn_mfma_f32_16x16x32_f16(hoA, wb[tt][0], kZero, 0, 0, 0);
    asm volatile("" : "+v"(hoB));
#pragma unroll
    for (int tt = 0; tt < 4; ++tt)
      cb[tt] = __builtin_amdgcn_mfma_f32_16x16x32_f16(hoB, wb[tt][1], kZero, 0, 0, 0);
  }

  for (int tc = 0; tc < TT; tc += 8) {
    // Issue all next-chunk u-loads; raw barriers never drain vmcnt, so they
    // stay in flight until the uc=un copy (8 steps of slack).
    const int tn = (tc + 8) & (TT - 1);
#pragma unroll
    for (int s = 0; s < 8; ++s) un[s] = Up[(size_t)(tn + s) * (BB * HH)];

#pragma unroll
    for (int s = 0; s < 8; ++s) {
      const int t = tc + s;

      // Top barrier: h_t cross-wave writes visible. Pre-issued MFMAs from
      // the previous iteration drain in the matrix pipe during the wait.
      asm volatile("s_waitcnt lgkmcnt(0)\n\ts_barrier" ::: "memory");

      // ---- 6 cross-wave chunks of h_t (broadcast b128 reads; compiler
      //      inserts incremental lgkmcnt before each consuming MFMA) ----
      const _Float16* hb = hbuf[t & 1];
      const half8_t h2 = *(const half8_t*)(hb + oX2);
      const half8_t h3 = *(const half8_t*)(hb + oX3);
      const half8_t h4 = *(const half8_t*)(hb + oX4);
      const half8_t h5 = *(const half8_t*)(hb + oX5);
      const half8_t h6 = *(const half8_t*)(hb + oX6);
      const half8_t h7 = *(const half8_t*)(hb + oX7);

      // ---- 24 MFMAs completing step t: chains ca (even) / cb (odd),
      //      dependent spacing 8 instructions = ~155 cy ----
#pragma unroll
      for (int tt = 0; tt < 4; ++tt)
        ca[tt] = __builtin_amdgcn_mfma_f32_16x16x32_f16(h2, wb[tt][2], ca[tt], 0, 0, 0);
#pragma unroll
      for (int tt = 0; tt < 4; ++tt)
        cb[tt] = __builtin_amdgcn_mfma_f32_16x16x32_f16(h3, wb[tt][3], cb[tt], 0, 0, 0);
#pragma unroll
      for (int tt = 0; tt < 4; ++tt)
        ca[tt] = __builtin_amdgcn_mfma_f32_16x16x32_f16(h4, wb[tt][4], ca[tt], 0, 0, 0);
#pragma unroll
      for (int tt = 0; tt < 4; ++tt)
        cb[tt] = __builtin_amdgcn_mfma_f32_16x16x32_f16(h5, wb[tt][5], cb[tt], 0, 0, 0);
#pragma unroll
      for (int tt = 0; tt < 4; ++tt)
        ca[tt] = __builtin_amdgcn_mfma_f32_16x16x32_f16(h6, wb[tt][6], ca[tt], 0, 0, 0);
#pragma unroll
      for (int tt = 0; tt < 4; ++tt)
        cb[tt] = __builtin_amdgcn_mfma_f32_16x16x32_f16(h7, wb[tt][7], cb[tt], 0, 0, 0);

      // ---- finalize: quad q owns tile q  =>  n = 64w + 16q + col = tid ----
      float yA = ca[0][0];
      yA = (quad == 1) ? ca[1][0] : yA;
      yA = (quad == 2) ? ca[2][0] : yA;
      yA = (quad == 3) ? ca[3][0] : yA;
      float yB = cb[0][0];
      yB = (quad == 1) ? cb[1][0] : yB;
      yB = (quad == 2) ? cb[2][0] : yB;
      yB = (quad == 3) ? cb[3][0] : yB;

      const float a = (float)uc[s] + (yA + yB);
      // tanh(a) = 1 - 2/(exp(2a)+1)
      const float e = __builtin_amdgcn_exp2f(a * 2.885390081777927f);  // 2*log2(e)
      hn = 1.f - 2.f * __builtin_amdgcn_rcpf(e + 1.f);

      // ---- write own h_{t+1}, read own chunks, pre-issue 8 MFMAs (t+1);
      //      kZero C-in starts fresh chains (no zero-init in the gap) ----
      _Float16* hb1 = (_Float16*)hbuf[(t + 1) & 1];
      hb1[tid] = (_Float16)hn;
      // Same-wave DS ordering: these reads see the wave's own writes above.
      half8_t hoA = *(const half8_t*)(hb1 + oO0);
      half8_t hoB = *(const half8_t*)(hb1 + oO1);
      asm volatile("" : "+v"(hoA));
#pragma unroll
      for (int tt = 0; tt < 4; ++tt)
        ca[tt] = __builtin_amdgcn_mfma_f32_16x16x32_f16(hoA, wb[tt][0], kZero, 0, 0, 0);
      asm volatile("" : "+v"(hoB));
#pragma unroll
      for (int tt = 0; tt < 4; ++tt)
        cb[tt] = __builtin_amdgcn_mfma_f32_16x16x32_f16(hoB, wb[tt][1], kZero, 0, 0, 0);
      // loop wraps to lgkmcnt(0)+barrier; the 8 MFMAs drain across it.
    }
#pragma unroll
    for (int s = 0; s < 8; ++s) uc[s] = un[s];
  }
  out[(size_t)b * HH + tid] = hn;
}

// ---------------------------------------------------------------------------
extern "C" void kernel_launch(void* const* d_in, const int* in_sizes, int n_in,
                              void* d_out, int out_size, void* d_ws, size_t ws_size,
                              hipStream_t stream) {
  const int*   source = (const int*)d_in[0];
  const float* emb    = (const float*)d_in[1];
  const float* Wih    = (const float*)d_in[2];
  const float* Whh    = (const float*)d_in[3];
  const float* bih    = (const float*)d_in[4];
  const float* bhh    = (const float*)d_in[5];
  float* out = (float*)d_out;

  char* ws = (char*)d_ws;
  _Float16* U    = (_Float16*)ws;                    // 2048*64*256*2 = 67,108,864 B
  _Float16* WihT = (_Float16*)(ws + 67108864);       // 131,072 B
  _Float16* WhhT = (_Float16*)(ws + 67239936);       // 131,072 B (total ~67.4 MB)

  prep_kernel<<<dim3(256), dim3(256), 0, stream>>>(Wih, Whh, WihT, WhhT);
  embed_gemm_kernel<<<dim3(TT, 4), dim3(256), 0, stream>>>(source, emb, WihT, bih, bhh, U);
  rnn_scan_kernel<<<dim3(BB), dim3(256), 0, stream>>>(U, WhhT, out);
}

// Round 8
// 876.061 us; speedup vs baseline: 1.1539x; 1.1539x over previous
//
#include <hip/hip_runtime.h>

#define TT 2048
#define BB 64
#define HH 256   // EMB == HID == 256
#define TPB 4    // t-values per embed block (B-tile staging amortization)

typedef _Float16 half2_t __attribute__((ext_vector_type(2)));
typedef _Float16 half8_t __attribute__((ext_vector_type(8)));
typedef float f32x4 __attribute__((ext_vector_type(4)));

// ---------------------------------------------------------------------------
// prep: transpose + fp16-convert W_ih/W_hh; optionally fp16-convert emb table.
// Blocks 0..255 do the transposes; all blocks grid-stride the emb convert.
// ---------------------------------------------------------------------------
__global__ void prep_kernel(const float* __restrict__ Wih, const float* __restrict__ Whh,
                            _Float16* __restrict__ WihT, _Float16* __restrict__ WhhT,
                            const float* __restrict__ emb, _Float16* __restrict__ emb16,
                            int do_emb) {
  if (blockIdx.x < 256) {
    const int n = blockIdx.x;   // output column
    const int k = threadIdx.x;  // input row
    WihT[n * HH + k] = (_Float16)Wih[k * HH + n];
    WhhT[n * HH + k] = (_Float16)Whh[k * HH + n];
  }
  if (do_emb) {
    const long nchunk = 32000L * HH / 8;  // half8 chunks
    for (long i = (long)blockIdx.x * blockDim.x + threadIdx.x; i < nchunk;
         i += (long)gridDim.x * blockDim.x) {
      const float4 x0 = *(const float4*)(emb + 8 * i);
      const float4 x1 = *(const float4*)(emb + 8 * i + 4);
      half8_t h;
      h[0] = (_Float16)x0.x; h[1] = (_Float16)x0.y;
      h[2] = (_Float16)x0.z; h[3] = (_Float16)x0.w;
      h[4] = (_Float16)x1.x; h[5] = (_Float16)x1.y;
      h[6] = (_Float16)x1.z; h[7] = (_Float16)x1.w;
      *(half8_t*)(emb16 + 8 * i) = h;
    }
  }
}

// ---------------------------------------------------------------------------
// Part A (v2): U[t][b][n] = (emb16[source[b][t]] @ W_ih)[n] + b_ih[n] + b_hh[n].
//   R17: fp16 emb table (halves gather bytes, kills 64 cvt/lane) + TPB=4
//   t-values per block (B-tile staged once per 4 t -> 4x fewer barriers and
//   4x less WihT re-read). fp32->fp16 rounding identical to the old in-kernel
//   cvt => absmax must repeat exactly.
// ---------------------------------------------------------------------------
__global__ __launch_bounds__(256, 2) void embed_gemm16_kernel(
    const int* __restrict__ source, const _Float16* __restrict__ emb16,
    const _Float16* __restrict__ WihT, const float* __restrict__ b_ih,
    const float* __restrict__ b_hh, _Float16* __restrict__ U) {
  const int t0 = blockIdx.x * TPB;
  const int nbase = blockIdx.y * 64;
  __shared__ __align__(16) _Float16 Bs[64][280];

  const int tid = threadIdx.x;
  for (int c = tid; c < 64 * 32; c += 256) {
    const int n = c >> 5;
    const int ko = (c & 31) * 8;
    *(half8_t*)&Bs[n][ko] = *(const half8_t*)(WihT + (size_t)(nbase + n) * HH + ko);
  }
  __syncthreads();

  const int lane = tid & 63;
  const int wave = tid >> 6;
  const int row16 = lane & 15;
  const int quad = lane >> 4;
  const int b = wave * 16 + row16;              // A-fragment row = batch

  // bias per n-tile (hoisted out of the t loop)
  float bias[4];
#pragma unroll
  for (int ct = 0; ct < 4; ++ct) {
    const int nn = nbase + ct * 16 + row16;
    bias[ct] = b_ih[nn] + b_hh[nn];
  }

  for (int ts = 0; ts < TPB; ++ts) {
    const int t = t0 + ts;
    const int src = source[b * TT + t];         // source is [B][T]
    const _Float16* arow = emb16 + (size_t)src * HH + quad * 8;

    f32x4 acc[4];
#pragma unroll
    for (int ct = 0; ct < 4; ++ct) acc[ct] = (f32x4){0.f, 0.f, 0.f, 0.f};

#pragma unroll
    for (int kt = 0; kt < 8; ++kt) {
      const half8_t af = *(const half8_t*)(arow + kt * 32);
#pragma unroll
      for (int ct = 0; ct < 4; ++ct) {
        const half8_t bf = *(const half8_t*)&Bs[ct * 16 + row16][quad * 8 + kt * 32];
        acc[ct] = __builtin_amdgcn_mfma_f32_16x16x32_f16(af, bf, acc[ct], 0, 0, 0);
      }
    }

#pragma unroll
    for (int ct = 0; ct < 4; ++ct) {
      const int nn = nbase + ct * 16 + row16;   // C col = lane&15
#pragma unroll
      for (int r = 0; r < 4; ++r) {
        const int bb = wave * 16 + quad * 4 + r;  // C row = quad*4 + reg
        U[((size_t)t * BB + bb) * HH + nn] = (_Float16)(acc[ct][r] + bias[ct]);
      }
    }
  }
}

// ---------------------------------------------------------------------------
// Part A (fallback, original): used only if ws_size can't hold emb16.
// ---------------------------------------------------------------------------
__global__ __launch_bounds__(256, 2) void embed_gemm_kernel(
    const int* __restrict__ source, const float* __restrict__ emb,
    const _Float16* __restrict__ WihT, const float* __restrict__ b_ih,
    const float* __restrict__ b_hh, _Float16* __restrict__ U) {
  const int t = blockIdx.x;
  const int nbase = blockIdx.y * 64;
  __shared__ __align__(16) _Float16 Bs[64][280];

  const int tid = threadIdx.x;
  for (int c = tid; c < 64 * 32; c += 256) {
    const int n = c >> 5;
    const int ko = (c & 31) * 8;
    *(half8_t*)&Bs[n][ko] = *(const half8_t*)(WihT + (size_t)(nbase + n) * HH + ko);
  }
  __syncthreads();

  const int lane = tid & 63;
  const int wave = tid >> 6;
  const int row16 = lane & 15;
  const int quad = lane >> 4;
  const int b = wave * 16 + row16;
  const int src = source[b * TT + t];
  const float* arow = emb + (size_t)src * HH + quad * 8;

  f32x4 acc[4];
#pragma unroll
  for (int ct = 0; ct < 4; ++ct) acc[ct] = (f32x4){0.f, 0.f, 0.f, 0.f};

#pragma unroll
  for (int kt = 0; kt < 8; ++kt) {
    const float4 x0 = *(const float4*)(arow + kt * 32);
    const float4 x1 = *(const float4*)(arow + kt * 32 + 4);
    half8_t af;
    af[0] = (_Float16)x0.x; af[1] = (_Float16)x0.y;
    af[2] = (_Float16)x0.z; af[3] = (_Float16)x0.w;
    af[4] = (_Float16)x1.x; af[5] = (_Float16)x1.y;
    af[6] = (_Float16)x1.z; af[7] = (_Float16)x1.w;
#pragma unroll
    for (int ct = 0; ct < 4; ++ct) {
      const half8_t bf = *(const half8_t*)&Bs[ct * 16 + row16][quad * 8 + kt * 32];
      acc[ct] = __builtin_amdgcn_mfma_f32_16x16x32_f16(af, bf, acc[ct], 0, 0, 0);
    }
  }

#pragma unroll
  for (int ct = 0; ct < 4; ++ct) {
    const int nn = nbase + ct * 16 + row16;
    const float bias = b_ih[nn] + b_hh[nn];
#pragma unroll
    for (int r = 0; r < 4; ++r) {
      const int bb = wave * 16 + quad * 4 + r;
      U[((size_t)t * BB + bb) * HH + nn] = (_Float16)(acc[ct][r] + bias);
    }
  }
}

// ---------------------------------------------------------------------------
// Part B: recurrence — R15 structure, UNCHANGED (best measured: scan 764 µs).
//   R16 post-mortem: split-chains + kZero C-in regressed to 1007 cy/step
//   (likely kZero forced per-step v_accvgpr_write zero fills); dep-spacing
//   theory falsified. Reverted verbatim to R15: cross-barrier own-chunk
//   pre-issue (8 MFMAs of step t+1 issued before the barrier), AGPR weights,
//   chunk rotation, one raw lgkmcnt(0);s_barrier per step, 8-step u prefetch.
// ---------------------------------------------------------------------------
__global__ __launch_bounds__(256)
__attribute__((amdgpu_waves_per_eu(1, 1)))
void rnn_scan_kernel(
    const _Float16* __restrict__ U, const _Float16* __restrict__ WhhT,
    float* __restrict__ out) {
  const int b = blockIdx.x;
  const int tid = threadIdx.x;
  const int w = tid >> 6;
  const int l = tid & 63;
  const int col = l & 15;    // n within tile
  const int quad = l >> 4;   // MFMA quad

  __shared__ __align__(16) _Float16 hbuf[2][HH];  // 1 KB ping-pong

  // wb[tt][j]: B-frag for n-tile 64w+16tt, k-chunk c=(2w+j)&7 (own chunks at
  // j=0,1). Lane reads WhhT[(64w+16tt+col)][32c + quad*8 .. +8] (16B aligned).
  half8_t wb[4][8];
#pragma unroll
  for (int tt = 0; tt < 4; ++tt) {
    const _Float16* base = WhhT + (size_t)(64 * w + 16 * tt + col) * HH + quad * 8;
#pragma unroll
    for (int j = 0; j < 8; ++j) {
      const int c = (2 * w + j) & 7;
      wb[tt][j] = *(const half8_t*)(base + 32 * c);
    }
  }
  // Pin into AGPRs ("a"): one-time v_accvgpr_write; MFMA reads B from AGPR.
  asm volatile("" : "+a"(wb[0][0]), "+a"(wb[0][1]), "+a"(wb[0][2]), "+a"(wb[0][3]),
                    "+a"(wb[0][4]), "+a"(wb[0][5]), "+a"(wb[0][6]), "+a"(wb[0][7]),
                    "+a"(wb[1][0]), "+a"(wb[1][1]), "+a"(wb[1][2]), "+a"(wb[1][3]),
                    "+a"(wb[1][4]), "+a"(wb[1][5]), "+a"(wb[1][6]), "+a"(wb[1][7]));
  asm volatile("" : "+a"(wb[2][0]), "+a"(wb[2][1]), "+a"(wb[2][2]), "+a"(wb[2][3]),
                    "+a"(wb[2][4]), "+a"(wb[2][5]), "+a"(wb[2][6]), "+a"(wb[2][7]),
                    "+a"(wb[3][0]), "+a"(wb[3][1]), "+a"(wb[3][2]), "+a"(wb[3][3]),
                    "+a"(wb[3][4]), "+a"(wb[3][5]), "+a"(wb[3][6]), "+a"(wb[3][7]));

  // h-read offsets (halfs): chunk (2w+j)&7 at 32*c + 8*quad.
  const int oO0 = 32 * ((2 * w + 0) & 7) + 8 * quad;  // own chunk j=0
  const int oO1 = 32 * ((2 * w + 1) & 7) + 8 * quad;  // own chunk j=1
  const int oX2 = 32 * ((2 * w + 2) & 7) + 8 * quad;
  const int oX3 = 32 * ((2 * w + 3) & 7) + 8 * quad;
  const int oX4 = 32 * ((2 * w + 4) & 7) + 8 * quad;
  const int oX5 = 32 * ((2 * w + 5) & 7) + 8 * quad;
  const int oX6 = 32 * ((2 * w + 6) & 7) + 8 * quad;
  const int oX7 = 32 * ((2 * w + 7) & 7) + 8 * quad;

  hbuf[0][tid] = (_Float16)0.f;  // h0 = 0

  // Thread tid finalizes output n = tid: u stream is per-thread contiguous.
  const _Float16* Up = U + b * HH + tid;  // step stride = BB*HH halfs
  _Float16 uc[8], un[8];
#pragma unroll
  for (int s = 0; s < 8; ++s) uc[s] = Up[(size_t)s * (BB * HH)];

  float hn = 0.f;
  f32x4 cacc[4];
#pragma unroll
  for (int tt = 0; tt < 4; ++tt) cacc[tt] = (f32x4){0.f, 0.f, 0.f, 0.f};

  // ---- prologue: own-chunk frags of h_0 + 8 pre-issued MFMAs (step 0) ----
  {
    half8_t hoA = *(const half8_t*)(hbuf[0] + oO0);
    half8_t hoB = *(const half8_t*)(hbuf[0] + oO1);
    asm volatile("" : "+v"(hoA), "+v"(hoB));
#pragma unroll
    for (int tt = 0; tt < 4; ++tt)
      cacc[tt] = __builtin_amdgcn_mfma_f32_16x16x32_f16(hoA, wb[tt][0], cacc[tt], 0, 0, 0);
#pragma unroll
    for (int tt = 0; tt < 4; ++tt)
      cacc[tt] = __builtin_amdgcn_mfma_f32_16x16x32_f16(hoB, wb[tt][1], cacc[tt], 0, 0, 0);
  }

  for (int tc = 0; tc < TT; tc += 8) {
    // Issue all next-chunk u-loads; raw barriers never drain vmcnt, so they
    // stay in flight until the uc=un copy (8 steps of slack).
    const int tn = (tc + 8) & (TT - 1);
#pragma unroll
    for (int s = 0; s < 8; ++s) un[s] = Up[(size_t)(tn + s) * (BB * HH)];

#pragma unroll
    for (int s = 0; s < 8; ++s) {
      const int t = tc + s;

      // Top barrier: h_t cross-wave writes visible. Pre-issued MFMAs from
      // the previous iteration drain in the matrix pipe during the wait.
      asm volatile("s_waitcnt lgkmcnt(0)\n\ts_barrier" ::: "memory");

      // ---- 6 cross-wave chunks of h_t (broadcast b128 reads) ----
      const _Float16* hb = hbuf[t & 1];
      half8_t h2 = *(const half8_t*)(hb + oX2);
      half8_t h3 = *(const half8_t*)(hb + oX3);
      half8_t h4 = *(const half8_t*)(hb + oX4);
      half8_t h5 = *(const half8_t*)(hb + oX5);
      half8_t h6 = *(const half8_t*)(hb + oX6);
      half8_t h7 = *(const half8_t*)(hb + oX7);
      asm volatile("" : "+v"(h2), "+v"(h3), "+v"(h4), "+v"(h5), "+v"(h6), "+v"(h7));

      // ---- 24 MFMAs completing step t (4 chains, chunk-major) ----
#pragma unroll
      for (int tt = 0; tt < 4; ++tt)
        cacc[tt] = __builtin_amdgcn_mfma_f32_16x16x32_f16(h2, wb[tt][2], cacc[tt], 0, 0, 0);
#pragma unroll
      for (int tt = 0; tt < 4; ++tt)
        cacc[tt] = __builtin_amdgcn_mfma_f32_16x16x32_f16(h3, wb[tt][3], cacc[tt], 0, 0, 0);
#pragma unroll
      for (int tt = 0; tt < 4; ++tt)
        cacc[tt] = __builtin_amdgcn_mfma_f32_16x16x32_f16(h4, wb[tt][4], cacc[tt], 0, 0, 0);
#pragma unroll
      for (int tt = 0; tt < 4; ++tt)
        cacc[tt] = __builtin_amdgcn_mfma_f32_16x16x32_f16(h5, wb[tt][5], cacc[tt], 0, 0, 0);
#pragma unroll
      for (int tt = 0; tt < 4; ++tt)
        cacc[tt] = __builtin_amdgcn_mfma_f32_16x16x32_f16(h6, wb[tt][6], cacc[tt], 0, 0, 0);
#pragma unroll
      for (int tt = 0; tt < 4; ++tt)
        cacc[tt] = __builtin_amdgcn_mfma_f32_16x16x32_f16(h7, wb[tt][7], cacc[tt], 0, 0, 0);

      // ---- finalize: quad q owns tile q  =>  n = 64w + 16q + col = tid ----
      float y = cacc[0][0];
      y = (quad == 1) ? cacc[1][0] : y;
      y = (quad == 2) ? cacc[2][0] : y;
      y = (quad == 3) ? cacc[3][0] : y;

      const float a = (float)uc[s] + y;
      // tanh(a) = 1 - 2/(exp(2a)+1)
      const float e = __builtin_amdgcn_exp2f(a * 2.885390081777927f);  // 2*log2(e)
      hn = 1.f - 2.f * __builtin_amdgcn_rcpf(e + 1.f);

      // ---- write own h_{t+1}, read own chunks, pre-issue 8 MFMAs (t+1) ----
      _Float16* hb1 = (_Float16*)hbuf[(t + 1) & 1];
      hb1[tid] = (_Float16)hn;
      // Same-wave DS ordering: these reads see the wave's own writes above.
      half8_t hoA = *(const half8_t*)(hb1 + oO0);
      half8_t hoB = *(const half8_t*)(hb1 + oO1);
      asm volatile("" : "+v"(hoA), "+v"(hoB));
#pragma unroll
      for (int tt = 0; tt < 4; ++tt) cacc[tt] = (f32x4){0.f, 0.f, 0.f, 0.f};
#pragma unroll
      for (int tt = 0; tt < 4; ++tt)
        cacc[tt] = __builtin_amdgcn_mfma_f32_16x16x32_f16(hoA, wb[tt][0], cacc[tt], 0, 0, 0);
#pragma unroll
      for (int tt = 0; tt < 4; ++tt)
        cacc[tt] = __builtin_amdgcn_mfma_f32_16x16x32_f16(hoB, wb[tt][1], cacc[tt], 0, 0, 0);
      // loop wraps to lgkmcnt(0)+barrier; the 8 MFMAs drain across it.
    }
#pragma unroll
    for (int s = 0; s < 8; ++s) uc[s] = un[s];
  }
  out[(size_t)b * HH + tid] = hn;
}

// ---------------------------------------------------------------------------
extern "C" void kernel_launch(void* const* d_in, const int* in_sizes, int n_in,
                              void* d_out, int out_size, void* d_ws, size_t ws_size,
                              hipStream_t stream) {
  const int*   source = (const int*)d_in[0];
  const float* emb    = (const float*)d_in[1];
  const float* Wih    = (const float*)d_in[2];
  const float* Whh    = (const float*)d_in[3];
  const float* bih    = (const float*)d_in[4];
  const float* bhh    = (const float*)d_in[5];
  float* out = (float*)d_out;

  char* ws = (char*)d_ws;
  _Float16* U     = (_Float16*)ws;                    // 2048*64*256*2 = 67,108,864 B
  _Float16* WihT  = (_Float16*)(ws + 67108864);       // 131,072 B
  _Float16* WhhT  = (_Float16*)(ws + 67239936);       // 131,072 B
  _Float16* emb16 = (_Float16*)(ws + 67371008);       // 32000*256*2 = 16,384,000 B
  const size_t need16 = 67371008u + 16384000u;        // 83,755,008 B

  if (ws_size >= need16) {
    prep_kernel<<<dim3(2048), dim3(256), 0, stream>>>(Wih, Whh, WihT, WhhT, emb, emb16, 1);
    embed_gemm16_kernel<<<dim3(TT / TPB, 4), dim3(256), 0, stream>>>(source, emb16, WihT, bih, bhh, U);
  } else {
    prep_kernel<<<dim3(256), dim3(256), 0, stream>>>(Wih, Whh, WihT, WhhT, emb, (_Float16*)WihT, 0);
    embed_gemm_kernel<<<dim3(TT, 4), dim3(256), 0, stream>>>(source, emb, WihT, bih, bhh, U);
  }
  rnn_scan_kernel<<<dim3(BB), dim3(256), 0, stream>>>(U, WhhT, out);
}